// Round 1
// baseline (975.949 us; speedup 1.0000x reference)
//
#include <hip/hip_runtime.h>

// Problem constants
#define BB 16
#define CC 32
#define HH 256
#define WW 256

// Tile config: each block does a 32-wide x 16-tall output tile, ALL 32 c_out.
// 256 threads, each thread owns 2 pixels (rows r and r+8) x 32 c_out accumulators.
#define TW 32
#define TH 16
#define CHUNK 8   // c_in chunk staged through LDS

template<bool RESID>
__global__ __launch_bounds__(256)
void conv_layer(const float* __restrict__ in,     // [B][C][H][W]
                const float* __restrict__ wgt,    // [C_out][C_in][3][3]
                const float* __restrict__ bias,   // [C]
                const float* __restrict__ gate,   // [B][C]
                const float* __restrict__ resid,  // x for layer 2 (or null)
                float* __restrict__ out)          // [B][C][H][W]
{
    __shared__ float xs[CHUNK][TH + 2][TW + 2];   // 8*18*34 = 4896 f = 19.1 KB
    __shared__ float ws[CC][CHUNK][12];           // 9 used, pad to 12 for b128 align
    __shared__ float gs[CC];
    __shared__ float bs[CC];

    const int t  = threadIdx.x;
    const int b  = blockIdx.z;
    const int y0 = blockIdx.y * TH;
    const int x0 = blockIdx.x * TW;

    if (t < CC) {
        float gv = gate[b * CC + t];
        gs[t] = gv > 0.f ? gv : 0.f;   // g = gate * (gate > 0)
        bs[t] = bias[t];
    }

    const int col = t & 31;    // 0..31
    const int row = t >> 5;    // 0..7

    float acc[2][CC];
    #pragma unroll
    for (int p = 0; p < 2; ++p)
        #pragma unroll
        for (int co = 0; co < CC; ++co) acc[p][co] = 0.f;

    for (int ci0 = 0; ci0 < CC; ci0 += CHUNK) {
        __syncthreads();  // protect xs/ws reuse across chunk iterations (and gs/bs 1st iter)

        // stage weight chunk: 32 co * 8 ci * 9 = 2304 floats
        for (int i = t; i < CC * CHUNK * 9; i += 256) {
            int co = i / (CHUNK * 9);
            int r  = i % (CHUNK * 9);
            int c  = r / 9;
            int kk = r % 9;
            ws[co][c][kk] = wgt[(co * CC + ci0 + c) * 9 + kk];
        }
        // stage x chunk with halo: 8 * 18 * 34 = 4896 floats (zero-pad boundary)
        for (int i = t; i < CHUNK * (TH + 2) * (TW + 2); i += 256) {
            int c  = i / ((TH + 2) * (TW + 2));
            int r  = i % ((TH + 2) * (TW + 2));
            int y  = r / (TW + 2);
            int xx = r % (TW + 2);
            int gy = y0 + y - 1;
            int gx = x0 + xx - 1;
            float v = 0.f;
            if (gy >= 0 && gy < HH && gx >= 0 && gx < WW)
                v = in[(((size_t)b * CC + ci0 + c) * HH + gy) * WW + gx];
            xs[c][y][xx] = v;
        }
        __syncthreads();

        for (int c = 0; c < CHUNK; ++c) {
            float xv0[9], xv1[9];
            #pragma unroll
            for (int dh = 0; dh < 3; ++dh)
                #pragma unroll
                for (int dw = 0; dw < 3; ++dw) {
                    xv0[dh * 3 + dw] = xs[c][row + dh    ][col + dw];
                    xv1[dh * 3 + dw] = xs[c][row + 8 + dh][col + dw];
                }
            #pragma unroll
            for (int co = 0; co < CC; ++co) {
                #pragma unroll
                for (int kk = 0; kk < 9; ++kk) {
                    float wv = ws[co][c][kk];
                    acc[0][co] += xv0[kk] * wv;
                    acc[1][co] += xv1[kk] * wv;
                }
            }
        }
    }

    // epilogue: (conv + bias) * g, relu, optional residual add
    #pragma unroll
    for (int p = 0; p < 2; ++p) {
        int gy = y0 + row + 8 * p;
        int gx = x0 + col;
        #pragma unroll
        for (int co = 0; co < CC; ++co) {
            float y = (acc[p][co] + bs[co]) * gs[co];
            y = y > 0.f ? y : 0.f;
            size_t oidx = (((size_t)b * CC + co) * HH + gy) * WW + gx;
            if (RESID) y += resid[oidx];
            out[oidx] = y;
        }
    }
}

extern "C" void kernel_launch(void* const* d_in, const int* in_sizes, int n_in,
                              void* d_out, int out_size, void* d_ws, size_t ws_size,
                              hipStream_t stream) {
    const float* x  = (const float*)d_in[0];
    const float* gv = (const float*)d_in[1];
    const float* w1 = (const float*)d_in[2];
    const float* b1 = (const float*)d_in[3];
    const float* w2 = (const float*)d_in[4];
    const float* b2 = (const float*)d_in[5];
    float* out = (float*)d_out;
    float* h1  = (float*)d_ws;   // needs B*C*H*W*4 = 128 MiB of scratch

    dim3 grid(WW / TW, HH / TH, BB);  // (8, 16, 16) = 2048 blocks
    conv_layer<false><<<grid, 256, 0, stream>>>(x,  w1, b1, gv, nullptr, h1);
    conv_layer<true ><<<grid, 256, 0, stream>>>(h1, w2, b2, gv, x,       out);
}

// Round 2
// 380.137 us; speedup vs baseline: 2.5674x; 2.5674x over previous
//
#include <hip/hip_runtime.h>

#define BB 16
#define CC 32
#define HH 256
#define WW 256

#define TW 32     // tile width (pixels) = MFMA N
#define TH 8      // tile rows per block (4 waves x 2 rows)
#define CIP 36    // padded ci per (y,x) in LDS: 36 ushort = 72 B = 18 words -> 2-way banks (free), 8B-aligned

// bf16x8 fragment = 4 VGPRs. Guide-verified typedef (short-based) for gfx950 bf16 MFMA.
typedef short bf16x8 __attribute__((ext_vector_type(8)));
typedef float f32x16 __attribute__((ext_vector_type(16)));

struct alignas(8)  U2 { unsigned x, y; };
struct alignas(16) U4 { U2 lo, hi; };

__device__ __forceinline__ unsigned short f2bf(float f) {
    unsigned u = __float_as_uint(f);
    u += 0x7fffu + ((u >> 16) & 1u);   // RNE
    return (unsigned short)(u >> 16);
}

// Pre-swizzle weights into per-lane MFMA A-fragment order, bf16:
// wq[layer][st(18)][half(2)][n=co(32)][j(8)], value = w[co][ci][pos]
// with pos = st>>1 (kh*3+kw), ci = (st&1)*16 + half*8 + j.
__global__ void wprep(const float* __restrict__ w1, const float* __restrict__ w2,
                      unsigned short* __restrict__ wq) {
    int idx = blockIdx.x * 256 + threadIdx.x;   // 0..9215
    if (idx >= 18 * 2 * 32 * 8) return;
    int j    = idx & 7;
    int n    = (idx >> 3) & 31;
    int half = (idx >> 8) & 1;
    int st   = idx >> 9;
    int s = st & 1, pos = st >> 1;
    int ci = s * 16 + half * 8 + j;
    int src = (n * CC + ci) * 9 + pos;
    wq[idx]        = f2bf(w1[src]);
    wq[9216 + idx] = f2bf(w2[src]);
}

// Implicit-GEMM conv3x3 (SAME) with fused bias*gate + relu.
// FIRST: in = fp32 NCHW x, out = bf16 NHWC h1.
// !FIRST: in = bf16 NHWC h1, out = fp32 NCHW (+= resid).
template<bool FIRST>
__global__ __launch_bounds__(256)
void conv_mfma(const void* __restrict__ in,
               const unsigned short* __restrict__ wq,  // this layer's 9216-elem frag table
               const float* __restrict__ bias,
               const float* __restrict__ gate,
               const float* __restrict__ resid,
               void* __restrict__ out)
{
    __shared__ unsigned short xs[TH + 2][TW + 2][CIP];   // 24480 B
    __shared__ float gs[CC], bs[CC];

    const int t  = threadIdx.x;
    const int b  = blockIdx.z;
    const int y0 = blockIdx.y * TH;
    const int x0 = blockIdx.x * TW;

    if (t < CC) {
        float gv = gate[b * CC + t];
        gs[t] = gv > 0.f ? gv : 0.f;
        bs[t] = bias[t];
    }

    const int lane = t & 63;
    const int wv   = t >> 6;       // wave 0..3
    const int col  = lane & 31;    // MFMA n (pixel) / A m (co) lane index
    const int half = lane >> 5;

    // Weight fragments: 18 x 16 B per lane, fully coalesced, L2-hot (36 KB table).
    bf16x8 wf[18];
    #pragma unroll
    for (int st = 0; st < 18; ++st) {
        U4 w = ((const U4*)wq)[(st * 2 + half) * 32 + col];
        wf[st] = __builtin_bit_cast(bf16x8, w);
    }

    // ---- stage input tile (10 x 34 x 32ci) into LDS channels-last bf16 ----
    if (FIRST) {
        const float* x = (const float*)in;
        for (int idx = t; idx < CC * (TH + 2) * (TW + 2); idx += 256) {
            int ci  = idx / ((TH + 2) * (TW + 2));
            int rem = idx - ci * ((TH + 2) * (TW + 2));
            int y   = rem / (TW + 2);
            int xx  = rem - y * (TW + 2);
            int gy = y0 + y - 1, gx = x0 + xx - 1;
            float v = 0.f;
            if (gy >= 0 && gy < HH && gx >= 0 && gx < WW)
                v = x[(((size_t)b * CC + ci) * HH + gy) * WW + gx];
            xs[y][xx][ci] = f2bf(v);
        }
    } else {
        const unsigned short* h = (const unsigned short*)in;
        for (int idx = t; idx < (TH + 2) * (TW + 2) * 4; idx += 256) {
            int q = idx & 3;
            int p = idx >> 2;
            int y  = p / (TW + 2);
            int xx = p - y * (TW + 2);
            int gy = y0 + y - 1, gx = x0 + xx - 1;
            U4 v; v.lo = {0u, 0u}; v.hi = {0u, 0u};
            if (gy >= 0 && gy < HH && gx >= 0 && gx < WW)
                v = *(const U4*)(h + (((size_t)b * HH + gy) * WW + gx) * CC + q * 8);
            *(U2*)&xs[y][xx][q * 8]     = v.lo;
            *(U2*)&xs[y][xx][q * 8 + 4] = v.hi;
        }
    }
    __syncthreads();

    // ---- K loop: 18 steps of 16 (pos = kh*3+kw outer, ci-half inner) ----
    f32x16 acc0 = {0,0,0,0,0,0,0,0,0,0,0,0,0,0,0,0};
    f32x16 acc1 = {0,0,0,0,0,0,0,0,0,0,0,0,0,0,0,0};
    const int r0 = wv * 2, r1 = wv * 2 + 1;

    #pragma unroll
    for (int st = 0; st < 18; ++st) {
        const int pos = st >> 1, s = st & 1;
        const int kh = pos / 3, kw = pos - kh * 3;
        const int ci0 = s * 16 + half * 8;
        U4 xa, xb;
        xa.lo = *(const U2*)&xs[r0 + kh][col + kw][ci0];
        xa.hi = *(const U2*)&xs[r0 + kh][col + kw][ci0 + 4];
        xb.lo = *(const U2*)&xs[r1 + kh][col + kw][ci0];
        xb.hi = *(const U2*)&xs[r1 + kh][col + kw][ci0 + 4];
        acc0 = __builtin_amdgcn_mfma_f32_32x32x16_bf16(wf[st], __builtin_bit_cast(bf16x8, xa), acc0, 0, 0, 0);
        acc1 = __builtin_amdgcn_mfma_f32_32x32x16_bf16(wf[st], __builtin_bit_cast(bf16x8, xb), acc1, 0, 0, 0);
    }

    // ---- epilogue: D[m=co][n=pixel], col = lane&31, co = (reg&3)+8*(reg>>2)+4*half ----
    if (FIRST) {
        unsigned short* o = (unsigned short*)out;
        size_t p0 = (((size_t)b * HH + y0 + r0) * WW + x0 + col) * CC;
        size_t p1 = (((size_t)b * HH + y0 + r1) * WW + x0 + col) * CC;
        #pragma unroll
        for (int reg = 0; reg < 16; ++reg) {
            int co = (reg & 3) + 8 * (reg >> 2) + 4 * half;
            float v0 = (acc0[reg] + bs[co]) * gs[co]; v0 = v0 > 0.f ? v0 : 0.f;
            float v1 = (acc1[reg] + bs[co]) * gs[co]; v1 = v1 > 0.f ? v1 : 0.f;
            o[p0 + co] = f2bf(v0);
            o[p1 + co] = f2bf(v1);
        }
    } else {
        float* o = (float*)out;
        #pragma unroll
        for (int reg = 0; reg < 16; ++reg) {
            int co = (reg & 3) + 8 * (reg >> 2) + 4 * half;
            size_t i0 = (((size_t)b * CC + co) * HH + y0 + r0) * WW + x0 + col;
            size_t i1 = (((size_t)b * CC + co) * HH + y0 + r1) * WW + x0 + col;
            float v0 = (acc0[reg] + bs[co]) * gs[co];
            float v1 = (acc1[reg] + bs[co]) * gs[co];
            o[i0] = fmaxf(v0, 0.f) + resid[i0];
            o[i1] = fmaxf(v1, 0.f) + resid[i1];
        }
    }
}

extern "C" void kernel_launch(void* const* d_in, const int* in_sizes, int n_in,
                              void* d_out, int out_size, void* d_ws, size_t ws_size,
                              hipStream_t stream) {
    const float* x  = (const float*)d_in[0];
    const float* gv = (const float*)d_in[1];
    const float* w1 = (const float*)d_in[2];
    const float* b1 = (const float*)d_in[3];
    const float* w2 = (const float*)d_in[4];
    const float* b2 = (const float*)d_in[5];
    float* out = (float*)d_out;

    unsigned short* h1 = (unsigned short*)d_ws;          // bf16 NHWC intermediate: 64 MiB
    unsigned short* wq = h1 + (size_t)BB * HH * WW * CC; // 2 x 9216 bf16 frag tables

    wprep<<<36, 256, 0, stream>>>(w1, w2, wq);

    dim3 grid(WW / TW, HH / TH, BB);  // (8, 32, 16) = 4096 blocks
    conv_mfma<true ><<<grid, 256, 0, stream>>>(x,  wq,        b1, gv, nullptr, h1);
    conv_mfma<false><<<grid, 256, 0, stream>>>(h1, wq + 9216, b2, gv, x,       out);
}